// Round 5
// baseline (738.480 us; speedup 1.0000x reference)
//
#include <hip/hip_runtime.h>
#include <cstdint>

#define H 64
#define EPR 32  // edges per round in gat_dst
#define SK 4    // edges per thread in scatter2_k

__device__ __forceinline__ float selu_f(float x) {
  const float sc = 1.0507009873554805f;
  const float al = 1.6732632423543772f;
  return x > 0.f ? sc * x : sc * al * (expf(x) - 1.f);
}

// ---------- dual GEMM: C0 = A@W0+b0, C1 = A@W1+b1 (A staged once) ----------
__global__ __launch_bounds__(256) void gemm64_dual(
    const float* __restrict__ A,
    const float* __restrict__ W0, const float* __restrict__ b0,
    const float* __restrict__ W1, const float* __restrict__ b1,
    float* __restrict__ C0, float* __restrict__ C1, int N) {
  __shared__ float Ws0[64 * 64];
  __shared__ float Ws1[64 * 64];
  __shared__ float As[64][65];
  __shared__ float bs0[64], bs1[64];

  const int tid = threadIdx.x;
  for (int i = tid; i < 1024; i += 256) {
    ((float4*)Ws0)[i] = ((const float4*)W0)[i];
    ((float4*)Ws1)[i] = ((const float4*)W1)[i];
  }
  if (tid < 64) { bs0[tid] = b0[tid]; bs1[tid] = b1[tid]; }

  const int row0 = blockIdx.x * 64;
  for (int i = tid; i < 1024; i += 256) {
    int r = i >> 4, c4 = i & 15;
    int row = row0 + r;
    float4 v = make_float4(0.f, 0.f, 0.f, 0.f);
    if (row < N) v = ((const float4*)(A + (size_t)row * H))[c4];
    As[r][c4 * 4 + 0] = v.x;
    As[r][c4 * 4 + 1] = v.y;
    As[r][c4 * 4 + 2] = v.z;
    As[r][c4 * 4 + 3] = v.w;
  }
  __syncthreads();

  const int g = tid & 3;
  const int r = tid >> 2;
  float a0[16], a1[16];
#pragma unroll
  for (int j = 0; j < 16; ++j) { a0[j] = bs0[g * 16 + j]; a1[j] = bs1[g * 16 + j]; }

  for (int k = 0; k < 64; ++k) {
    float ak = As[r][k];
    const float4* w0r = (const float4*)&Ws0[k * 64 + g * 16];
    const float4* w1r = (const float4*)&Ws1[k * 64 + g * 16];
#pragma unroll
    for (int j4 = 0; j4 < 4; ++j4) {
      float4 w0 = w0r[j4], w1 = w1r[j4];
      a0[j4 * 4 + 0] += ak * w0.x; a0[j4 * 4 + 1] += ak * w0.y;
      a0[j4 * 4 + 2] += ak * w0.z; a0[j4 * 4 + 3] += ak * w0.w;
      a1[j4 * 4 + 0] += ak * w1.x; a1[j4 * 4 + 1] += ak * w1.y;
      a1[j4 * 4 + 2] += ak * w1.z; a1[j4 * 4 + 3] += ak * w1.w;
    }
  }

  const int row = row0 + r;
  if (row < N) {
    float4* c0 = (float4*)(C0 + (size_t)row * H + g * 16);
    float4* c1 = (float4*)(C1 + (size_t)row * H + g * 16);
#pragma unroll
    for (int j4 = 0; j4 < 4; ++j4) {
      c0[j4] = make_float4(a0[j4 * 4 + 0], a0[j4 * 4 + 1], a0[j4 * 4 + 2], a0[j4 * 4 + 3]);
      c1[j4] = make_float4(a1[j4 * 4 + 0], a1[j4 * 4 + 1], a1[j4 * 4 + 2], a1[j4 * 4 + 3]);
    }
  }
}

// ---------- CSR build (dual-graph merged kernels) ----------
__global__ __launch_bounds__(256) void hist2_k(
    const int* __restrict__ ed1, int E1r, int n1e, int* __restrict__ c1,
    const int* __restrict__ ed2, int E2r, int n2e, int* __restrict__ c2,
    int split) {
  int b = blockIdx.x;
  const int* ed; int Er, ne; int* cnt; int e;
  if (b < split) { ed = ed1; Er = E1r; ne = n1e; cnt = c1; e = b * 256 + threadIdx.x; }
  else { ed = ed2; Er = E2r; ne = n2e; cnt = c2; e = (b - split) * 256 + threadIdx.x; }
  if (e >= ne) return;
  int d = (e < Er) ? ed[e] : (e - Er);
  atomicAdd(&cnt[d], 1);
}

__global__ __launch_bounds__(256) void scan_partial2(
    const int* __restrict__ cnt1, int n1, int* __restrict__ psum1, int* __restrict__ bsum1,
    const int* __restrict__ cnt2, int n2, int* __restrict__ psum2, int* __restrict__ bsum2,
    int split) {
  __shared__ int sh[256];
  int b = blockIdx.x;
  const int* cnt; int n; int* psum; int* bsum; int lb;
  if (b < split) { cnt = cnt1; n = n1; psum = psum1; bsum = bsum1; lb = b; }
  else { cnt = cnt2; n = n2; psum = psum2; bsum = bsum2; lb = b - split; }
  int i = lb * 256 + threadIdx.x;
  int tid = threadIdx.x;
  sh[tid] = (i < n) ? cnt[i] : 0;
  __syncthreads();
  for (int off = 1; off < 256; off <<= 1) {
    int t = (tid >= off) ? sh[tid - off] : 0;
    __syncthreads();
    if (tid >= off) sh[tid] += t;
    __syncthreads();
  }
  if (i < n) psum[i] = sh[tid];
  if (tid == 255) bsum[lb] = sh[255];
}

// exclusive scan of both bsum arrays, single block
__global__ __launch_bounds__(256) void scan_bsums2(
    int* __restrict__ bsum1, int nb1, int* __restrict__ bsum2, int nb2) {
  __shared__ int sh[256];
  const int tid = threadIdx.x;
  for (int which = 0; which < 2; ++which) {
    int* bsum = which ? bsum2 : bsum1;
    int nb = which ? nb2 : nb1;
    int run = 0;
    for (int start = 0; start < nb; start += 256) {
      int i = start + tid;
      int v = (i < nb) ? bsum[i] : 0;
      __syncthreads();
      sh[tid] = v;
      __syncthreads();
      for (int off = 1; off < 256; off <<= 1) {
        int t = (tid >= off) ? sh[tid - off] : 0;
        __syncthreads();
        if (tid >= off) sh[tid] += t;
        __syncthreads();
      }
      if (i < nb) bsum[i] = run + sh[tid] - v;  // exclusive
      run += sh[255];
      __syncthreads();
    }
  }
}

__global__ __launch_bounds__(256) void finalize_scan2(
    const int* __restrict__ cnt1, const int* __restrict__ psum1,
    const int* __restrict__ bsum1, int n1, int* __restrict__ rp1, int* __restrict__ wofs1,
    const int* __restrict__ cnt2, const int* __restrict__ psum2,
    const int* __restrict__ bsum2, int n2, int* __restrict__ rp2, int* __restrict__ wofs2,
    int split) {
  int b = blockIdx.x;
  const int *cnt, *psum, *bsum; int n; int *rp, *wofs; int lb;
  if (b < split) { cnt = cnt1; psum = psum1; bsum = bsum1; n = n1; rp = rp1; wofs = wofs1; lb = b; }
  else { cnt = cnt2; psum = psum2; bsum = bsum2; n = n2; rp = rp2; wofs = wofs2; lb = b - split; }
  int i = lb * 256 + threadIdx.x;
  if (i >= n) return;
  int val = psum[i] + bsum[lb];
  rp[i + 1] = val;
  wofs[i] = val - cnt[i];
}

// SK edges per thread: batch independent atomics (MLP), then nt scatter stores
__global__ __launch_bounds__(256) void scatter2_k(
    const int* __restrict__ es1, const int* __restrict__ ed1, int E1r, int n1e,
    int* __restrict__ wofs1, int* __restrict__ csr1,
    const int* __restrict__ es2, const int* __restrict__ ed2, int E2r, int n2e,
    int* __restrict__ wofs2, int* __restrict__ csr2, int split) {
  int b = blockIdx.x;
  const int *es, *ed; int Er, ne; int *wofs, *csr; int tid0, stride;
  if (b < split) {
    es = es1; ed = ed1; Er = E1r; ne = n1e; wofs = wofs1; csr = csr1;
    tid0 = b * 256 + threadIdx.x; stride = split * 256;
  } else {
    es = es2; ed = ed2; Er = E2r; ne = n2e; wofs = wofs2; csr = csr2;
    tid0 = (b - split) * 256 + threadIdx.x; stride = ((int)gridDim.x - split) * 256;
  }
  int pos[SK], sv[SK];
#pragma unroll
  for (int k = 0; k < SK; ++k) {
    int e = tid0 + k * stride;  // coalesced within wave at each k
    if (e < ne) {
      int s, d;
      if (e < Er) { s = es[e]; d = ed[e]; } else { s = e - Er; d = s; }
      sv[k] = s;
      pos[k] = atomicAdd(&wofs[d], 1);  // SK independent RMWs in flight
    } else {
      pos[k] = -1;
    }
  }
#pragma unroll
  for (int k = 0; k < SK; ++k) {
    if (pos[k] >= 0) __builtin_nontemporal_store(sv[k], &csr[pos[k]]);
  }
}

// ---------- fused GATv2: one dst per 64-thread block ----------
__global__ __launch_bounds__(64) void gat_dst(
    const int* __restrict__ row_ptr, const int* __restrict__ csr_src,
    const float* __restrict__ xl, const float* __restrict__ xr,
    const float* __restrict__ att, const float* __restrict__ bias,
    float* __restrict__ out, int n_dst) {
  __shared__ __align__(16) float tile[EPR * 64];  // 8 KB, xor-swizzled columns

  const int d = blockIdx.x;
  const int h = threadIdx.x;  // 0..63
  const float xr_h = xr[(size_t)d * H + h];
  const float att_h = att[h];
  const int beg = row_ptr[d];
  const int end = row_ptr[d + 1];

  const int hx = h << 2;                              // byte col before swizzle
  const int tr = h & 31;                              // transpose: my edge row
  const int trbase = (tr << 8) ^ ((tr & 15) << 4);    // swizzled row base (bytes)
  const int tro = (h >> 5) * 8;                       // half-row chunk start

  float m = -3.0e38f, s = 0.f, acc = 0.f;

  for (int base = beg; base < end; base += EPR) {
    int cnt = end - base;
    if (cnt > EPR) cnt = EPR;
    float v[EPR];

    // ---- phase 1: coalesced row gathers + score contributions ----
#pragma unroll
    for (int q = 0; q < EPR / 4; ++q) {
      if (q * 4 < cnt) {  // wave-uniform
#pragma unroll
        for (int i = 0; i < 4; ++i) {
          const int k = q * 4 + i;
          int j = k < cnt ? k : cnt - 1;     // clamped dup (harmless overwrite)
          int src = csr_src[base + j];       // wave-uniform -> scalar load
          float vv = xl[(size_t)src * H + h];
          v[k] = vv;
          float p = vv + xr_h;
          p = fmaxf(p, 0.f) + 0.2f * fminf(p, 0.f);  // leaky relu
          *(float*)((char*)tile + (k << 8) + (hx ^ ((k & 15) << 4))) = p * att_h;
        }
      }
    }

    // ---- transpose read: per-edge score, half-row per lane ----
    float t0 = 0.f, t1 = 0.f, t2 = 0.f, t3 = 0.f;
#pragma unroll
    for (int c = 0; c < 8; ++c) {
      float4 q4 = *(const float4*)((const char*)tile + (trbase ^ ((tro + c) << 4)));
      t0 += q4.x; t1 += q4.y; t2 += q4.z; t3 += q4.w;
    }
    float t = (t0 + t1) + (t2 + t3);
    t += __shfl_xor(t, 32, 64);          // combine the two half-rows
    t = (tr < cnt) ? t : -3.0e38f;       // mask invalid edges (kills stale/NaN)

    // ---- batched softmax over this round's <=32 edges ----
    float M = t;
#pragma unroll
    for (int mk = 1; mk <= 16; mk <<= 1) M = fmaxf(M, __shfl_xor(M, mk, 64));
    float e = __expf(t - M);             // 0 for masked lanes
    float S = e;
#pragma unroll
    for (int mk = 1; mk <= 16; mk <<= 1) S += __shfl_xor(S, mk, 64);
    if (h < 32) tile[h] = e;             // w_k into consumed tile row 0

    // ---- flash-style merge + phase 2 weighted sum ----
    float nm = fmaxf(m, M);
    float a_old = __expf(m - nm);
    float a_new = __expf(M - nm);
    float P = 0.f;
#pragma unroll
    for (int q = 0; q < EPR / 4; ++q) {
      if (q * 4 < cnt) {  // wave-uniform; w==0 for k>=cnt, v finite (dup)
        float4 w4 = ((const float4*)tile)[q];  // broadcast read
        P += w4.x * v[q * 4 + 0];
        P += w4.y * v[q * 4 + 1];
        P += w4.z * v[q * 4 + 2];
        P += w4.w * v[q * 4 + 3];
      }
    }
    s = s * a_old + S * a_new;
    acc = acc * a_old + P * a_new;
    m = nm;
  }

  float o = acc / (s + 1e-16f) + bias[h];
  out[(size_t)d * H + h] = selu_f(o);
}

// ---------- launch ----------
extern "C" void kernel_launch(void* const* d_in, const int* in_sizes, int n_in,
                              void* d_out, int out_size, void* d_ws, size_t ws_size,
                              hipStream_t stream) {
  const float* x_user = (const float*)d_in[0];
  const float* x_movie = (const float*)d_in[1];
  const int* e_u2m = (const int*)d_in[2];
  const int* e_m2u = (const int*)d_in[3];
  const float* Wl = (const float*)d_in[4];
  const float* bl = (const float*)d_in[5];
  const float* Wr = (const float*)d_in[6];
  const float* br = (const float*)d_in[7];
  const float* att = (const float*)d_in[8];
  const float* bias = (const float*)d_in[9];

  const int n_user = in_sizes[0] / H;
  const int n_movie = in_sizes[1] / H;
  const int E1 = in_sizes[2] / 2;  // user->movie
  const int E2 = in_sizes[3] / 2;  // movie->user
  const int n_loop = n_user < n_movie ? n_user : n_movie;
  const int nE1 = E1 + n_loop;
  const int nE2 = E2 + n_loop;

  float* ws = (float*)d_ws;
  size_t o = 0;
  float* xl_u2m = ws + o; o += (size_t)n_user * H;
  float* xr_u2m = ws + o; o += (size_t)n_movie * H;
  float* xl_m2u = ws + o; o += (size_t)n_movie * H;
  float* xr_m2u = ws + o; o += (size_t)n_user * H;

  // zero region: cnt1 | row_ptr1 | cnt2 | row_ptr2 (contiguous)
  size_t zero_base = o;
  int* cnt1 = (int*)(ws + o); o += n_movie;
  int* rp1  = (int*)(ws + o); o += n_movie + 1;
  int* cnt2 = (int*)(ws + o); o += n_user;
  int* rp2  = (int*)(ws + o); o += n_user + 1;
  const size_t zero_bytes = (o - zero_base) * sizeof(float);

  int* psum1 = (int*)(ws + o); o += n_movie;
  int* wofs1 = (int*)(ws + o); o += n_movie;
  int* psum2 = (int*)(ws + o); o += n_user;
  int* wofs2 = (int*)(ws + o); o += n_user;
  int* bsum1 = (int*)(ws + o); o += 1024;
  int* bsum2 = (int*)(ws + o); o += 1024;
  int* csr1  = (int*)(ws + o); o += nE1;
  int* csr2  = (int*)(ws + o); o += nE2;

  float* out_u = (float*)d_out;
  float* out_m = out_u + (size_t)n_user * H;

  const int gu = (n_user + 63) / 64;
  const int gm = (n_movie + 63) / 64;
  const int nb1 = (n_movie + 255) / 256;
  const int nb2 = (n_user + 255) / 256;
  const int ebe1 = (nE1 + 255) / 256;
  const int ebe2 = (nE2 + 255) / 256;
  const int sbe1 = (nE1 + 256 * SK - 1) / (256 * SK);  // scatter blocks (SK edges/thread)
  const int sbe2 = (nE2 + 256 * SK - 1) / (256 * SK);

  // ---- CSR build (layer-invariant, once per launch, merged dual-graph) ----
  hipMemsetAsync(ws + zero_base, 0, zero_bytes, stream);
  hist2_k<<<ebe1 + ebe2, 256, 0, stream>>>(
      e_u2m + E1, E1, nE1, cnt1, e_m2u + E2, E2, nE2, cnt2, ebe1);
  scan_partial2<<<nb1 + nb2, 256, 0, stream>>>(
      cnt1, n_movie, psum1, bsum1, cnt2, n_user, psum2, bsum2, nb1);
  scan_bsums2<<<1, 256, 0, stream>>>(bsum1, nb1, bsum2, nb2);
  finalize_scan2<<<nb1 + nb2, 256, 0, stream>>>(
      cnt1, psum1, bsum1, n_movie, rp1, wofs1,
      cnt2, psum2, bsum2, n_user, rp2, wofs2, nb1);
  scatter2_k<<<sbe1 + sbe2, 256, 0, stream>>>(
      e_u2m, e_u2m + E1, E1, nE1, wofs1, csr1,
      e_m2u, e_m2u + E2, E2, nE2, wofs2, csr2, sbe1);

  for (int l = 0; l < 2; ++l) {
    const float* cu = (l == 0) ? x_user : out_u;
    const float* cm = (l == 0) ? x_movie : out_m;
    const int p0 = l * 2 + 0;  // user->movie params
    const int p1 = l * 2 + 1;  // movie->user params

    gemm64_dual<<<gu, 256, 0, stream>>>(
        cu, Wl + (size_t)p0 * H * H, bl + (size_t)p0 * H,
        Wr + (size_t)p1 * H * H, br + (size_t)p1 * H, xl_u2m, xr_m2u, n_user);
    gemm64_dual<<<gm, 256, 0, stream>>>(
        cm, Wr + (size_t)p0 * H * H, br + (size_t)p0 * H,
        Wl + (size_t)p1 * H * H, bl + (size_t)p1 * H, xr_u2m, xl_m2u, n_movie);

    gat_dst<<<n_movie, 64, 0, stream>>>(
        rp1, csr1, xl_u2m, xr_u2m, att + (size_t)p0 * H, bias + (size_t)p0 * H, out_m, n_movie);
    gat_dst<<<n_user, 64, 0, stream>>>(
        rp2, csr2, xl_m2u, xr_m2u, att + (size_t)p1 * H, bias + (size_t)p1 * H, out_u, n_user);
  }
}

// Round 6
// 549.928 us; speedup vs baseline: 1.3429x; 1.3429x over previous
//
#include <hip/hip_runtime.h>
#include <cstdint>

#define H 64
#define EPR 32   // edges per round in gat_dst
#define NB 120   // partition blocks per graph (pass A/C chunking)

__device__ __forceinline__ float selu_f(float x) {
  const float sc = 1.0507009873554805f;
  const float al = 1.6732632423543772f;
  return x > 0.f ? sc * x : sc * al * (expf(x) - 1.f);
}

// ---------- dual GEMM: C0 = A@W0+b0, C1 = A@W1+b1 (A staged once) ----------
__global__ __launch_bounds__(256) void gemm64_dual(
    const float* __restrict__ A,
    const float* __restrict__ W0, const float* __restrict__ b0,
    const float* __restrict__ W1, const float* __restrict__ b1,
    float* __restrict__ C0, float* __restrict__ C1, int N) {
  __shared__ float Ws0[64 * 64];
  __shared__ float Ws1[64 * 64];
  __shared__ float As[64][65];
  __shared__ float bs0[64], bs1[64];

  const int tid = threadIdx.x;
  for (int i = tid; i < 1024; i += 256) {
    ((float4*)Ws0)[i] = ((const float4*)W0)[i];
    ((float4*)Ws1)[i] = ((const float4*)W1)[i];
  }
  if (tid < 64) { bs0[tid] = b0[tid]; bs1[tid] = b1[tid]; }

  const int row0 = blockIdx.x * 64;
  for (int i = tid; i < 1024; i += 256) {
    int r = i >> 4, c4 = i & 15;
    int row = row0 + r;
    float4 v = make_float4(0.f, 0.f, 0.f, 0.f);
    if (row < N) v = ((const float4*)(A + (size_t)row * H))[c4];
    As[r][c4 * 4 + 0] = v.x;
    As[r][c4 * 4 + 1] = v.y;
    As[r][c4 * 4 + 2] = v.z;
    As[r][c4 * 4 + 3] = v.w;
  }
  __syncthreads();

  const int g = tid & 3;
  const int r = tid >> 2;
  float a0[16], a1[16];
#pragma unroll
  for (int j = 0; j < 16; ++j) { a0[j] = bs0[g * 16 + j]; a1[j] = bs1[g * 16 + j]; }

  for (int k = 0; k < 64; ++k) {
    float ak = As[r][k];
    const float4* w0r = (const float4*)&Ws0[k * 64 + g * 16];
    const float4* w1r = (const float4*)&Ws1[k * 64 + g * 16];
#pragma unroll
    for (int j4 = 0; j4 < 4; ++j4) {
      float4 w0 = w0r[j4], w1 = w1r[j4];
      a0[j4 * 4 + 0] += ak * w0.x; a0[j4 * 4 + 1] += ak * w0.y;
      a0[j4 * 4 + 2] += ak * w0.z; a0[j4 * 4 + 3] += ak * w0.w;
      a1[j4 * 4 + 0] += ak * w1.x; a1[j4 * 4 + 1] += ak * w1.y;
      a1[j4 * 4 + 2] += ak * w1.z; a1[j4 * 4 + 3] += ak * w1.w;
    }
  }

  const int row = row0 + r;
  if (row < N) {
    float4* c0 = (float4*)(C0 + (size_t)row * H + g * 16);
    float4* c1 = (float4*)(C1 + (size_t)row * H + g * 16);
#pragma unroll
    for (int j4 = 0; j4 < 4; ++j4) {
      c0[j4] = make_float4(a0[j4 * 4 + 0], a0[j4 * 4 + 1], a0[j4 * 4 + 2], a0[j4 * 4 + 3]);
      c1[j4] = make_float4(a1[j4 * 4 + 0], a1[j4 * 4 + 1], a1[j4 * 4 + 2], a1[j4 * 4 + 3]);
    }
  }
}

// ---------- Pass A: per-block bucket histograms (LDS only, no device atomics) ----------
__global__ __launch_bounds__(256) void bucket_hist(
    const int* __restrict__ ed1, int E1r, int n1e, int sh1, int B1, int* __restrict__ mat1,
    const int* __restrict__ ed2, int E2r, int n2e, int sh2, int B2, int* __restrict__ mat2) {
  __shared__ int hist[256];
  int b = blockIdx.x;
  const int* ed; int Er, ne, sh, Bn, blk; int* mat;
  if (b < NB) { ed = ed1; Er = E1r; ne = n1e; sh = sh1; Bn = B1; mat = mat1; blk = b; }
  else { ed = ed2; Er = E2r; ne = n2e; sh = sh2; Bn = B2; mat = mat2; blk = b - NB; }
  for (int i = threadIdx.x; i < Bn; i += 256) hist[i] = 0;
  __syncthreads();
  int chunk = (ne + NB - 1) / NB;
  int lo = blk * chunk, hi = lo + chunk;
  if (hi > ne) hi = ne;
  for (int e = lo + threadIdx.x; e < hi; e += 256) {
    int d = (e < Er) ? ed[e] : (e - Er);
    atomicAdd(&hist[d >> sh], 1);  // LDS atomic
  }
  __syncthreads();
  for (int i = threadIdx.x; i < Bn; i += 256) mat[(size_t)i * NB + blk] = hist[i];
}

// ---------- scan chain (reused on flattened [bucket][block] matrices) ----------
__global__ __launch_bounds__(256) void scan_partial2(
    const int* __restrict__ cnt1, int n1, int* __restrict__ psum1, int* __restrict__ bsum1,
    const int* __restrict__ cnt2, int n2, int* __restrict__ psum2, int* __restrict__ bsum2,
    int split) {
  __shared__ int sh[256];
  int b = blockIdx.x;
  const int* cnt; int n; int* psum; int* bsum; int lb;
  if (b < split) { cnt = cnt1; n = n1; psum = psum1; bsum = bsum1; lb = b; }
  else { cnt = cnt2; n = n2; psum = psum2; bsum = bsum2; lb = b - split; }
  int i = lb * 256 + threadIdx.x;
  int tid = threadIdx.x;
  sh[tid] = (i < n) ? cnt[i] : 0;
  __syncthreads();
  for (int off = 1; off < 256; off <<= 1) {
    int t = (tid >= off) ? sh[tid - off] : 0;
    __syncthreads();
    if (tid >= off) sh[tid] += t;
    __syncthreads();
  }
  if (i < n) psum[i] = sh[tid];
  if (tid == 255) bsum[lb] = sh[255];
}

__global__ __launch_bounds__(256) void scan_bsums2(
    int* __restrict__ bsum1, int nb1, int* __restrict__ bsum2, int nb2) {
  __shared__ int sh[256];
  const int tid = threadIdx.x;
  for (int which = 0; which < 2; ++which) {
    int* bsum = which ? bsum2 : bsum1;
    int nb = which ? nb2 : nb1;
    int run = 0;
    for (int start = 0; start < nb; start += 256) {
      int i = start + tid;
      int v = (i < nb) ? bsum[i] : 0;
      __syncthreads();
      sh[tid] = v;
      __syncthreads();
      for (int off = 1; off < 256; off <<= 1) {
        int t = (tid >= off) ? sh[tid - off] : 0;
        __syncthreads();
        if (tid >= off) sh[tid] += t;
        __syncthreads();
      }
      if (i < nb) bsum[i] = run + sh[tid] - v;  // exclusive
      run += sh[255];
      __syncthreads();
    }
  }
}

// exclusive scan output: excl[i] = inclusive - cnt
__global__ __launch_bounds__(256) void finalize_excl2(
    const int* __restrict__ cnt1, const int* __restrict__ psum1,
    const int* __restrict__ bsum1, int n1, int* __restrict__ excl1,
    const int* __restrict__ cnt2, const int* __restrict__ psum2,
    const int* __restrict__ bsum2, int n2, int* __restrict__ excl2, int split) {
  int b = blockIdx.x;
  const int *cnt, *psum, *bsum; int n; int* excl; int lb;
  if (b < split) { cnt = cnt1; psum = psum1; bsum = bsum1; n = n1; excl = excl1; lb = b; }
  else { cnt = cnt2; psum = psum2; bsum = bsum2; n = n2; excl = excl2; lb = b - split; }
  int i = lb * 256 + threadIdx.x;
  if (i >= n) return;
  excl[i] = psum[i] + bsum[lb] - cnt[i];
}

// ---------- Pass C: partition edges into bucket order via private LDS cursors ----------
// part[] entry: (dstlocal << 18) | src   (src < 2^18, dstlocal < 2^9)
__global__ __launch_bounds__(256) void bucket_part(
    const int* __restrict__ es1, const int* __restrict__ ed1, int E1r, int n1e,
    int sh1, int B1, const int* __restrict__ excl1, unsigned* __restrict__ part1,
    const int* __restrict__ es2, const int* __restrict__ ed2, int E2r, int n2e,
    int sh2, int B2, const int* __restrict__ excl2, unsigned* __restrict__ part2) {
  __shared__ int cur[256];
  int b = blockIdx.x;
  const int *es, *ed, *excl; int Er, ne, sh, Bn, blk; unsigned* part;
  if (b < NB) { es = es1; ed = ed1; Er = E1r; ne = n1e; sh = sh1; Bn = B1; excl = excl1; part = part1; blk = b; }
  else { es = es2; ed = ed2; Er = E2r; ne = n2e; sh = sh2; Bn = B2; excl = excl2; part = part2; blk = b - NB; }
  for (int i = threadIdx.x; i < Bn; i += 256) cur[i] = excl[(size_t)i * NB + blk];
  __syncthreads();
  int chunk = (ne + NB - 1) / NB;
  int lo = blk * chunk, hi = lo + chunk;
  if (hi > ne) hi = ne;
  const unsigned lmask = (1u << sh) - 1u;
  for (int e = lo + threadIdx.x; e < hi; e += 256) {
    int s, d;
    if (e < Er) { s = es[e]; d = ed[e]; } else { s = e - Er; d = s; }
    int bkt = d >> sh;
    int pos = atomicAdd(&cur[bkt], 1);  // LDS atomic; (block,bucket) ranges disjoint
    part[pos] = (((unsigned)d & lmask) << 18) | (unsigned)s;
  }
}

// ---------- Pass D: per-bucket LDS counting sort -> row_ptr + csr ----------
__global__ __launch_bounds__(256) void bucket_sort(
    const unsigned* __restrict__ part1, const int* __restrict__ excl1,
    int n1e, int sh1, int B1, int nd1, int* __restrict__ rp1, int* __restrict__ csr1,
    const unsigned* __restrict__ part2, const int* __restrict__ excl2,
    int n2e, int sh2, int B2, int nd2, int* __restrict__ rp2, int* __restrict__ csr2) {
  __shared__ int cnt_s[512];
  __shared__ int scan_s[512];
  int b = blockIdx.x;
  const unsigned* part; const int* excl; int ne, sh, Bn, nd, bkt; int *rp, *csr;
  if (b < B1) { part = part1; excl = excl1; ne = n1e; sh = sh1; Bn = B1; nd = nd1; rp = rp1; csr = csr1; bkt = b; }
  else { part = part2; excl = excl2; ne = n2e; sh = sh2; Bn = B2; nd = nd2; rp = rp2; csr = csr2; bkt = b - B1; }
  const int tid = threadIdx.x;
  const int dbase = bkt << sh;
  const int R = 1 << sh;
  int rcap = nd - dbase;
  if (rcap > R) rcap = R;
  const int base = excl[(size_t)bkt * NB];
  const int endv = (bkt == Bn - 1) ? ne : excl[(size_t)(bkt + 1) * NB];

  cnt_s[tid] = 0; cnt_s[256 + tid] = 0;
  __syncthreads();
  for (int i = base + tid; i < endv; i += 256)
    atomicAdd(&cnt_s[part[i] >> 18], 1);
  __syncthreads();
  scan_s[tid] = cnt_s[tid];
  scan_s[256 + tid] = cnt_s[256 + tid];
  __syncthreads();
  // inclusive scan, lower 256
  for (int off = 1; off < 256; off <<= 1) {
    int t = (tid >= off) ? scan_s[tid - off] : 0;
    __syncthreads();
    if (tid >= off) scan_s[tid] += t;
    __syncthreads();
  }
  // inclusive scan, upper 256
  for (int off = 1; off < 256; off <<= 1) {
    int t = (tid >= off) ? scan_s[256 + tid - off] : 0;
    __syncthreads();
    if (tid >= off) scan_s[256 + tid] += t;
    __syncthreads();
  }
  int lowtot = scan_s[255];   // lower-half total (untouched by upper scan)
  scan_s[256 + tid] += lowtot;
  __syncthreads();
  // emit row_ptr (inclusive) and init write cursors (exclusive)
  if (tid < rcap) rp[dbase + tid + 1] = base + scan_s[tid];
  if (256 + tid < rcap) rp[dbase + 256 + tid + 1] = base + scan_s[256 + tid];
  cnt_s[tid] = base + scan_s[tid] - cnt_s[tid];
  cnt_s[256 + tid] = base + scan_s[256 + tid] - cnt_s[256 + tid];
  if (tid == 0 && bkt == 0) rp[0] = 0;
  __syncthreads();
  for (int i = base + tid; i < endv; i += 256) {
    unsigned p = part[i];
    int dl = p >> 18;
    int pos = atomicAdd(&cnt_s[dl], 1);  // LDS atomic
    csr[pos] = (int)(p & 0x3FFFFu);      // writes confined to this bucket's window
  }
}

// ---------- fused GATv2: one dst per 64-thread block ----------
__global__ __launch_bounds__(64) void gat_dst(
    const int* __restrict__ row_ptr, const int* __restrict__ csr_src,
    const float* __restrict__ xl, const float* __restrict__ xr,
    const float* __restrict__ att, const float* __restrict__ bias,
    float* __restrict__ out, int n_dst) {
  __shared__ __align__(16) float tile[EPR * 64];  // 8 KB, xor-swizzled columns

  const int d = blockIdx.x;
  const int h = threadIdx.x;  // 0..63
  const float xr_h = xr[(size_t)d * H + h];
  const float att_h = att[h];
  const int beg = row_ptr[d];
  const int end = row_ptr[d + 1];

  const int hx = h << 2;
  const int tr = h & 31;
  const int trbase = (tr << 8) ^ ((tr & 15) << 4);
  const int tro = (h >> 5) * 8;

  float m = -3.0e38f, s = 0.f, acc = 0.f;

  for (int base = beg; base < end; base += EPR) {
    int cnt = end - base;
    if (cnt > EPR) cnt = EPR;
    float v[EPR];

#pragma unroll
    for (int q = 0; q < EPR / 4; ++q) {
      if (q * 4 < cnt) {
#pragma unroll
        for (int i = 0; i < 4; ++i) {
          const int k = q * 4 + i;
          int j = k < cnt ? k : cnt - 1;
          int src = csr_src[base + j];
          float vv = xl[(size_t)src * H + h];
          v[k] = vv;
          float p = vv + xr_h;
          p = fmaxf(p, 0.f) + 0.2f * fminf(p, 0.f);
          *(float*)((char*)tile + (k << 8) + (hx ^ ((k & 15) << 4))) = p * att_h;
        }
      }
    }

    float t0 = 0.f, t1 = 0.f, t2 = 0.f, t3 = 0.f;
#pragma unroll
    for (int c = 0; c < 8; ++c) {
      float4 q4 = *(const float4*)((const char*)tile + (trbase ^ ((tro + c) << 4)));
      t0 += q4.x; t1 += q4.y; t2 += q4.z; t3 += q4.w;
    }
    float t = (t0 + t1) + (t2 + t3);
    t += __shfl_xor(t, 32, 64);
    t = (tr < cnt) ? t : -3.0e38f;

    float M = t;
#pragma unroll
    for (int mk = 1; mk <= 16; mk <<= 1) M = fmaxf(M, __shfl_xor(M, mk, 64));
    float e = __expf(t - M);
    float S = e;
#pragma unroll
    for (int mk = 1; mk <= 16; mk <<= 1) S += __shfl_xor(S, mk, 64);
    if (h < 32) tile[h] = e;

    float nm = fmaxf(m, M);
    float a_old = __expf(m - nm);
    float a_new = __expf(M - nm);
    float P = 0.f;
#pragma unroll
    for (int q = 0; q < EPR / 4; ++q) {
      if (q * 4 < cnt) {
        float4 w4 = ((const float4*)tile)[q];
        P += w4.x * v[q * 4 + 0];
        P += w4.y * v[q * 4 + 1];
        P += w4.z * v[q * 4 + 2];
        P += w4.w * v[q * 4 + 3];
      }
    }
    s = s * a_old + S * a_new;
    acc = acc * a_old + P * a_new;
    m = nm;
  }

  float o = acc / (s + 1e-16f) + bias[h];
  out[(size_t)d * H + h] = selu_f(o);
}

// ---------- launch ----------
extern "C" void kernel_launch(void* const* d_in, const int* in_sizes, int n_in,
                              void* d_out, int out_size, void* d_ws, size_t ws_size,
                              hipStream_t stream) {
  const float* x_user = (const float*)d_in[0];
  const float* x_movie = (const float*)d_in[1];
  const int* e_u2m = (const int*)d_in[2];
  const int* e_m2u = (const int*)d_in[3];
  const float* Wl = (const float*)d_in[4];
  const float* bl = (const float*)d_in[5];
  const float* Wr = (const float*)d_in[6];
  const float* br = (const float*)d_in[7];
  const float* att = (const float*)d_in[8];
  const float* bias = (const float*)d_in[9];

  const int n_user = in_sizes[0] / H;
  const int n_movie = in_sizes[1] / H;
  const int E1 = in_sizes[2] / 2;  // user->movie (dst = movie)
  const int E2 = in_sizes[3] / 2;  // movie->user (dst = user)
  const int n_loop = n_user < n_movie ? n_user : n_movie;
  const int nE1 = E1 + n_loop;
  const int nE2 = E2 + n_loop;

  // bucket params: movies get 128-dst buckets, users 512-dst buckets
  const int SHM = 7, SHU = 9;
  const int Bm = (n_movie + (1 << SHM) - 1) >> SHM;  // ~157
  const int Bu = (n_user + (1 << SHU) - 1) >> SHU;   // ~196
  const int nmatM = Bm * NB, nmatU = Bu * NB;
  const int nbm = (nmatM + 255) / 256, nbu = (nmatU + 255) / 256;

  float* ws = (float*)d_ws;
  size_t o = 0;
  float* xl_u2m = ws + o; o += (size_t)n_user * H;
  float* xr_u2m = ws + o; o += (size_t)n_movie * H;
  float* xl_m2u = ws + o; o += (size_t)n_movie * H;
  float* xr_m2u = ws + o; o += (size_t)n_user * H;

  int* matM  = (int*)(ws + o); o += nmatM;
  int* psumM = (int*)(ws + o); o += nmatM;
  int* exclM = (int*)(ws + o); o += nmatM;
  int* matU  = (int*)(ws + o); o += nmatU;
  int* psumU = (int*)(ws + o); o += nmatU;
  int* exclU = (int*)(ws + o); o += nmatU;
  int* bsumM = (int*)(ws + o); o += 1024;
  int* bsumU = (int*)(ws + o); o += 1024;
  unsigned* partM = (unsigned*)(ws + o); o += nE1;
  unsigned* partU = (unsigned*)(ws + o); o += nE2;
  int* csr1 = (int*)(ws + o); o += nE1;
  int* csr2 = (int*)(ws + o); o += nE2;
  int* rp1  = (int*)(ws + o); o += n_movie + 1;
  int* rp2  = (int*)(ws + o); o += n_user + 1;

  float* out_u = (float*)d_out;
  float* out_m = out_u + (size_t)n_user * H;

  const int gu = (n_user + 63) / 64;
  const int gm = (n_movie + 63) / 64;

  // ---- CSR build: deterministic two-level bucket sort, zero device atomics ----
  bucket_hist<<<2 * NB, 256, 0, stream>>>(
      e_u2m + E1, E1, nE1, SHM, Bm, matM,
      e_m2u + E2, E2, nE2, SHU, Bu, matU);
  scan_partial2<<<nbm + nbu, 256, 0, stream>>>(
      matM, nmatM, psumM, bsumM, matU, nmatU, psumU, bsumU, nbm);
  scan_bsums2<<<1, 256, 0, stream>>>(bsumM, nbm, bsumU, nbu);
  finalize_excl2<<<nbm + nbu, 256, 0, stream>>>(
      matM, psumM, bsumM, nmatM, exclM,
      matU, psumU, bsumU, nmatU, exclU, nbm);
  bucket_part<<<2 * NB, 256, 0, stream>>>(
      e_u2m, e_u2m + E1, E1, nE1, SHM, Bm, exclM, partM,
      e_m2u, e_m2u + E2, E2, nE2, SHU, Bu, exclU, partU);
  bucket_sort<<<Bm + Bu, 256, 0, stream>>>(
      partM, exclM, nE1, SHM, Bm, n_movie, rp1, csr1,
      partU, exclU, nE2, SHU, Bu, n_user, rp2, csr2);

  for (int l = 0; l < 2; ++l) {
    const float* cu = (l == 0) ? x_user : out_u;
    const float* cm = (l == 0) ? x_movie : out_m;
    const int p0 = l * 2 + 0;  // user->movie params
    const int p1 = l * 2 + 1;  // movie->user params

    gemm64_dual<<<gu, 256, 0, stream>>>(
        cu, Wl + (size_t)p0 * H * H, bl + (size_t)p0 * H,
        Wr + (size_t)p1 * H * H, br + (size_t)p1 * H, xl_u2m, xr_m2u, n_user);
    gemm64_dual<<<gm, 256, 0, stream>>>(
        cm, Wr + (size_t)p0 * H * H, br + (size_t)p0 * H,
        Wl + (size_t)p1 * H * H, bl + (size_t)p1 * H, xr_u2m, xl_m2u, n_movie);

    gat_dst<<<n_movie, 64, 0, stream>>>(
        rp1, csr1, xl_u2m, xr_u2m, att + (size_t)p0 * H, bias + (size_t)p0 * H, out_m, n_movie);
    gat_dst<<<n_user, 64, 0, stream>>>(
        rp2, csr2, xl_m2u, xr_m2u, att + (size_t)p1 * H, bias + (size_t)p1 * H, out_u, n_user);
  }
}